// Round 1
// baseline (1179.767 us; speedup 1.0000x reference)
//
#include <hip/hip_runtime.h>
#include <hip/hip_bf16.h>

// GCN: h = x@W; deg/dinv with self-loops; S[i] = h[i]*dinv[i] + sum_{e:src->i} h[src]*dinv[src];
// node_out = relu(dinv[i]*S[i] + b_conv); pooled mean per graph; logits = pooled@W_cls + b_cls.
// All norm algebra folded so the per-edge work is gather(64B) + 16 atomic f32 adds.

#define NNODES 100000
#define NEDGES 3200000
#define FIN    512
#define HID    16
#define NG     64
#define WSTRIDE 20  // LDS row stride for W: 16 would put the 4 k-slots on one bank (4-way); 20 -> 2-way (free)

// ---------------- GEMM: h[N,16] = x[N,512] @ W[512,16] ------------------
// wave = 16 row-slots x 4 k-slots; 4 consecutive lanes cover 64B of one row -> full coalescing.
// Each lane handles 2 rows (r, r+16). W lives in LDS (padded). Reduce over the 4 k-slots (2 shfls).
__global__ __launch_bounds__(256) void k_gemm(const float* __restrict__ x,
                                              const float* __restrict__ W,
                                              float* __restrict__ h) {
  __shared__ float Wl[FIN * WSTRIDE];
  const int t = threadIdx.x;
  for (int i = t; i < FIN * 4; i += 256) {          // 2048 float4s of W
    float4 w = ((const float4*)W)[i];
    *((float4*)&Wl[(i >> 2) * WSTRIDE + (i & 3) * 4]) = w;
  }
  __syncthreads();
  const int lane = t & 63;
  const int ks = lane & 3;      // k-slot
  const int rs = lane >> 6 == 0 ? (lane >> 2) : 0;  // row-slot 0..15
  const int gw = (blockIdx.x << 2) + (t >> 6);      // global wave id
  const int base = gw * 32;
  if (base >= NNODES) return;
  const int r0 = base + rs;
  const int r1 = r0 + 16;
  const int c0 = (r0 < NNODES) ? r0 : (NNODES - 1); // clamp, mask at write
  const int c1 = (r1 < NNODES) ? r1 : (NNODES - 1);
  const float* xr0 = x + (size_t)c0 * FIN;
  const float* xr1 = x + (size_t)c1 * FIN;
  float4 acc0[4], acc1[4];
#pragma unroll
  for (int cg = 0; cg < 4; ++cg) {
    acc0[cg] = make_float4(0.f, 0.f, 0.f, 0.f);
    acc1[cg] = make_float4(0.f, 0.f, 0.f, 0.f);
  }
#pragma unroll 4
  for (int ch = 0; ch < 32; ++ch) {
    const int kb = ch * 16 + ks * 4;
    float4 xv0 = *(const float4*)(xr0 + kb);
    float4 xv1 = *(const float4*)(xr1 + kb);
#pragma unroll
    for (int kk = 0; kk < 4; ++kk) {
      const float* wr = &Wl[(kb + kk) * WSTRIDE];
      const float4 w0 = *(const float4*)(wr);
      const float4 w1 = *(const float4*)(wr + 4);
      const float4 w2 = *(const float4*)(wr + 8);
      const float4 w3 = *(const float4*)(wr + 12);
      const float a0 = ((const float*)&xv0)[kk];
      const float a1 = ((const float*)&xv1)[kk];
      acc0[0] += w0 * a0; acc0[1] += w1 * a0; acc0[2] += w2 * a0; acc0[3] += w3 * a0;
      acc1[0] += w0 * a1; acc1[1] += w1 * a1; acc1[2] += w2 * a1; acc1[3] += w3 * a1;
    }
  }
#pragma unroll
  for (int cg = 0; cg < 4; ++cg) {
    float* p0 = (float*)&acc0[cg];
    float* p1 = (float*)&acc1[cg];
#pragma unroll
    for (int j = 0; j < 4; ++j) {
      p0[j] += __shfl_xor(p0[j], 1); p0[j] += __shfl_xor(p0[j], 2);
      p1[j] += __shfl_xor(p1[j], 1); p1[j] += __shfl_xor(p1[j], 2);
    }
  }
  if (ks == 0) {
    if (r0 < NNODES) {
      float4* o = (float4*)&h[(size_t)r0 * HID];
      o[0] = acc0[0]; o[1] = acc0[1]; o[2] = acc0[2]; o[3] = acc0[3];
    }
    if (r1 < NNODES) {
      float4* o = (float4*)&h[(size_t)r1 * HID];
      o[0] = acc1[0]; o[1] = acc1[1]; o[2] = acc1[2]; o[3] = acc1[3];
    }
  }
}

// ---------------- init: deg=1 (self-loop), zero graph accumulators ----------------
__global__ void k_init(float* __restrict__ deg, float* __restrict__ gacc) {
  int i = blockIdx.x * blockDim.x + threadIdx.x;
  if (i < NNODES) deg[i] = 1.0f;
  if (i < NG * HID + NG) gacc[i] = 0.0f;   // gsum (1024) ++ gcnt (64), contiguous
}

// ---------------- in-degree scatter ----------------
__global__ void k_deg(const int* __restrict__ dst, float* __restrict__ deg) {
  int e = blockIdx.x * blockDim.x + threadIdx.x;
  if (e < NEDGES) atomicAdd(&deg[dst[e]], 1.0f);
}

// ---------------- scale: dinv=rsqrt(deg); h <- h*dinv (=hs); S <- hs (self-loop term) ----------------
__global__ void k_scale(float* __restrict__ h, const float* __restrict__ deg,
                        float* __restrict__ dinv, float* __restrict__ S) {
  int t = blockIdx.x * blockDim.x + threadIdx.x;
  if (t >= NNODES * 4) return;
  int i = t >> 2, j = t & 3;
  float di = rsqrtf(deg[i]);     // deg >= 1 always (self-loop), matches where(deg>0,...)
  if (j == 0) dinv[i] = di;
  float4 hv = ((float4*)h)[i * 4 + j];
  hv *= di;
  ((float4*)h)[i * 4 + j] = hv;
  ((float4*)S)[i * 4 + j] = hv;
}

// ---------------- edge scatter: S[dst] += hs[src]; 4 threads/edge, float4 each ----------------
__global__ void k_edge(const int* __restrict__ src, const int* __restrict__ dst,
                       const float* __restrict__ hs, float* __restrict__ S) {
  int t = blockIdx.x * blockDim.x + threadIdx.x;
  if (t >= NEDGES * 4) return;
  int e = t >> 2, j = t & 3;
  int s = src[e], d = dst[e];
  float4 v = ((const float4*)hs)[s * 4 + j];
  float* o = &S[(size_t)d * HID + j * 4];
  atomicAdd(o + 0, v.x);
  atomicAdd(o + 1, v.y);
  atomicAdd(o + 2, v.z);
  atomicAdd(o + 3, v.w);
}

// ---------------- node out = relu(dinv*S + b_conv); segmented pool (batch is sorted) ----------------
__global__ void k_pool(const float* __restrict__ S, const float* __restrict__ dinv,
                       const float* __restrict__ bconv, const int* __restrict__ batch,
                       float* __restrict__ gsum, float* __restrict__ gcnt) {
  int i = blockIdx.x * blockDim.x + threadIdx.x;
  const bool valid = i < NNODES;
  const int ic = valid ? i : (NNODES - 1);
  const float di = dinv[ic];
  float4 a[4];
#pragma unroll
  for (int cg = 0; cg < 4; ++cg) {
    float4 sv = ((const float4*)S)[ic * 4 + cg];
    float4 bv = ((const float4*)bconv)[cg];
    a[cg].x = fmaxf(sv.x * di + bv.x, 0.f);
    a[cg].y = fmaxf(sv.y * di + bv.y, 0.f);
    a[cg].z = fmaxf(sv.z * di + bv.z, 0.f);
    a[cg].w = fmaxf(sv.w * di + bv.w, 0.f);
    if (!valid) a[cg] = make_float4(0.f, 0.f, 0.f, 0.f);
  }
  int g = valid ? batch[ic] : -1;
  int g0 = __shfl(g, 0);
  int g63 = __shfl(g, 63);
  if (g0 == g63 && g0 >= 0) {
    // whole wave in one graph (batch sorted): butterfly-reduce the 16 channels
#pragma unroll
    for (int cg = 0; cg < 4; ++cg) {
      float* p = (float*)&a[cg];
#pragma unroll
      for (int j = 0; j < 4; ++j) {
        float v = p[j];
        v += __shfl_xor(v, 1);  v += __shfl_xor(v, 2);  v += __shfl_xor(v, 4);
        v += __shfl_xor(v, 8);  v += __shfl_xor(v, 16); v += __shfl_xor(v, 32);
        p[j] = v;
      }
    }
    if ((threadIdx.x & 63) == 0) {
#pragma unroll
      for (int cg = 0; cg < 4; ++cg) {
        float* p = (float*)&a[cg];
        atomicAdd(&gsum[g0 * HID + cg * 4 + 0], p[0]);
        atomicAdd(&gsum[g0 * HID + cg * 4 + 1], p[1]);
        atomicAdd(&gsum[g0 * HID + cg * 4 + 2], p[2]);
        atomicAdd(&gsum[g0 * HID + cg * 4 + 3], p[3]);
      }
      atomicAdd(&gcnt[g0], 64.0f);
    }
  } else if (valid) {            // graph-boundary wave (rare): per-lane atomics
#pragma unroll
    for (int cg = 0; cg < 4; ++cg) {
      float* p = (float*)&a[cg];
      atomicAdd(&gsum[g * HID + cg * 4 + 0], p[0]);
      atomicAdd(&gsum[g * HID + cg * 4 + 1], p[1]);
      atomicAdd(&gsum[g * HID + cg * 4 + 2], p[2]);
      atomicAdd(&gsum[g * HID + cg * 4 + 3], p[3]);
    }
    atomicAdd(&gcnt[g], 1.0f);
  }
}

// ---------------- final: logits[g,k] = (gsum[g]/max(cnt,1)) @ W_cls + b_cls ----------------
__global__ void k_final(const float* __restrict__ gsum, const float* __restrict__ gcnt,
                        const float* __restrict__ Wcls, const float* __restrict__ bcls,
                        float* __restrict__ out) {
  int t = threadIdx.x;
  if (t >= NG * 2) return;
  int g = t >> 1, k = t & 1;
  float cnt = fmaxf(gcnt[g], 1.0f);
  float s = 0.f;
#pragma unroll
  for (int c = 0; c < HID; ++c) s += gsum[g * HID + c] * Wcls[c * 2 + k];
  out[t] = s / cnt + bcls[k];
}

extern "C" void kernel_launch(void* const* d_in, const int* in_sizes, int n_in,
                              void* d_out, int out_size, void* d_ws, size_t ws_size,
                              hipStream_t stream) {
  const float* x     = (const float*)d_in[0];
  const float* W     = (const float*)d_in[1];
  const float* bconv = (const float*)d_in[2];
  const float* Wcls  = (const float*)d_in[3];
  const float* bcls  = (const float*)d_in[4];
  const int*   ei    = (const int*)d_in[5];   // [2, E] flat: src then dst
  const int*   batch = (const int*)d_in[6];

  float* ws   = (float*)d_ws;
  float* h    = ws;                                   // 1.6M floats (becomes hs in-place)
  float* S    = ws + (size_t)NNODES * HID;            // 1.6M floats
  float* deg  = ws + (size_t)2 * NNODES * HID;        // 100K
  float* dinv = deg + NNODES;                         // 100K
  float* gsum = dinv + NNODES;                        // 1024
  float* gcnt = gsum + NG * HID;                      // 64  (contiguous with gsum)

  const int* esrc = ei;
  const int* edst = ei + NEDGES;

  k_init <<<(NNODES + 255) / 256, 256, 0, stream>>>(deg, gsum);
  k_deg  <<<(NEDGES + 255) / 256, 256, 0, stream>>>(edst, deg);
  k_gemm <<<(NNODES + 127) / 128, 256, 0, stream>>>(x, W, h);
  k_scale<<<(NNODES * 4 + 255) / 256, 256, 0, stream>>>(h, deg, dinv, S);
  k_edge <<<(NEDGES * 4 + 255) / 256, 256, 0, stream>>>(esrc, edst, h, S);
  k_pool <<<(NNODES + 255) / 256, 256, 0, stream>>>(S, dinv, bconv, batch, gsum, gcnt);
  k_final<<<1, 128, 0, stream>>>(gsum, gcnt, Wcls, bcls, (float*)d_out);
}

// Round 2
// 856.533 us; speedup vs baseline: 1.3774x; 1.3774x over previous
//
#include <hip/hip_runtime.h>
#include <hip/hip_bf16.h>

// GCN via counting-sort CSR + gather (no fp32 far-atomics).
// hs = (x@W)*dinv; S[i] = hs[i] + sum_{src->i} hs[src]; node = relu(dinv[i]*S[i]+b);
// pool mean per graph; logits = pooled@W_cls + b_cls.

#define NNODES 100000
#define NEDGES 3200000
#define FIN    512
#define HID    16
#define NG     64
#define WSTRIDE 20

// ---------------- zero: cnt[N] ints + graph accumulators ----------------
__global__ void k_zero(int* __restrict__ cnt, float* __restrict__ gacc) {
  int i = blockIdx.x * blockDim.x + threadIdx.x;
  if (i < NNODES) cnt[i] = 0;
  if (i < NG * HID + NG) gacc[i] = 0.0f;
}

// ---------------- in-degree histogram (int atomics) ----------------
__global__ void k_hist(const int* __restrict__ dst, int* __restrict__ cnt) {
  int e = blockIdx.x * blockDim.x + threadIdx.x;
  if (e < NEDGES) atomicAdd(&cnt[dst[e]], 1);
}

// ---------------- scan level 1: per-256 block exclusive scan ----------------
__global__ void k_scanA(const int* __restrict__ cnt, int* __restrict__ off,
                        int* __restrict__ bsum) {
  __shared__ int sm[256];
  int t = threadIdx.x;
  int i = blockIdx.x * 256 + t;
  int v = (i < NNODES) ? cnt[i] : 0;
  sm[t] = v; __syncthreads();
#pragma unroll
  for (int d = 1; d < 256; d <<= 1) {
    int x = (t >= d) ? sm[t - d] : 0;
    __syncthreads(); sm[t] += x; __syncthreads();
  }
  if (i < NNODES) off[i] = sm[t] - v;
  if (t == 255) bsum[blockIdx.x] = sm[255];
}

// ---------------- scan level 2: single block over 391 block sums (in place) ----------------
__global__ void k_scanB(int* __restrict__ bsum, int nb) {
  __shared__ int sm[512];
  int t = threadIdx.x;
  int v = (t < nb) ? bsum[t] : 0;
  sm[t] = v; __syncthreads();
#pragma unroll
  for (int d = 1; d < 512; d <<= 1) {
    int x = (t >= d) ? sm[t - d] : 0;
    __syncthreads(); sm[t] += x; __syncthreads();
  }
  if (t < nb) bsum[t] = sm[t] - v;   // exclusive
}

// ---------------- scan level 3: add block offsets; init cursor; dinv ----------------
__global__ void k_scanC(int* __restrict__ off, const int* __restrict__ bsum,
                        const int* __restrict__ cnt, int* __restrict__ cursor,
                        float* __restrict__ dinv) {
  int i = blockIdx.x * blockDim.x + threadIdx.x;
  if (i >= NNODES) return;
  int o = off[i] + bsum[i >> 8];
  off[i] = o;
  cursor[i] = o;
  dinv[i] = rsqrtf((float)(cnt[i] + 1));   // +1 self-loop; deg>=1 always
}

// ---------------- GEMM: hs[N,16] = (x[N,512] @ W[512,16]) * dinv[row] ----------------
__global__ __launch_bounds__(256) void k_gemm(const float* __restrict__ x,
                                              const float* __restrict__ W,
                                              const float* __restrict__ dinv,
                                              float* __restrict__ hs) {
  __shared__ float Wl[FIN * WSTRIDE];
  const int t = threadIdx.x;
  for (int i = t; i < FIN * 4; i += 256) {
    float4 w = ((const float4*)W)[i];
    *((float4*)&Wl[(i >> 2) * WSTRIDE + (i & 3) * 4]) = w;
  }
  __syncthreads();
  const int lane = t & 63;
  const int ks = lane & 3;
  const int rs = lane >> 2;           // 0..15
  const int gw = (blockIdx.x << 2) + (t >> 6);
  const int base = gw * 32;
  if (base >= NNODES) return;
  const int r0 = base + rs;
  const int r1 = r0 + 16;
  const int c0 = (r0 < NNODES) ? r0 : (NNODES - 1);
  const int c1 = (r1 < NNODES) ? r1 : (NNODES - 1);
  const float* xr0 = x + (size_t)c0 * FIN;
  const float* xr1 = x + (size_t)c1 * FIN;
  float4 acc0[4], acc1[4];
#pragma unroll
  for (int cg = 0; cg < 4; ++cg) {
    acc0[cg] = make_float4(0.f, 0.f, 0.f, 0.f);
    acc1[cg] = make_float4(0.f, 0.f, 0.f, 0.f);
  }
#pragma unroll 4
  for (int ch = 0; ch < 32; ++ch) {
    const int kb = ch * 16 + ks * 4;
    float4 xv0 = *(const float4*)(xr0 + kb);
    float4 xv1 = *(const float4*)(xr1 + kb);
#pragma unroll
    for (int kk = 0; kk < 4; ++kk) {
      const float* wr = &Wl[(kb + kk) * WSTRIDE];
      const float4 w0 = *(const float4*)(wr);
      const float4 w1 = *(const float4*)(wr + 4);
      const float4 w2 = *(const float4*)(wr + 8);
      const float4 w3 = *(const float4*)(wr + 12);
      const float a0 = ((const float*)&xv0)[kk];
      const float a1 = ((const float*)&xv1)[kk];
      acc0[0] += w0 * a0; acc0[1] += w1 * a0; acc0[2] += w2 * a0; acc0[3] += w3 * a0;
      acc1[0] += w0 * a1; acc1[1] += w1 * a1; acc1[2] += w2 * a1; acc1[3] += w3 * a1;
    }
  }
#pragma unroll
  for (int cg = 0; cg < 4; ++cg) {
    float* p0 = (float*)&acc0[cg];
    float* p1 = (float*)&acc1[cg];
#pragma unroll
    for (int j = 0; j < 4; ++j) {
      p0[j] += __shfl_xor(p0[j], 1); p0[j] += __shfl_xor(p0[j], 2);
      p1[j] += __shfl_xor(p1[j], 1); p1[j] += __shfl_xor(p1[j], 2);
    }
  }
  if (ks == 0) {
    if (r0 < NNODES) {
      const float di = dinv[r0];
      float4* o = (float4*)&hs[(size_t)r0 * HID];
      o[0] = make_float4(acc0[0].x*di, acc0[0].y*di, acc0[0].z*di, acc0[0].w*di);
      o[1] = make_float4(acc0[1].x*di, acc0[1].y*di, acc0[1].z*di, acc0[1].w*di);
      o[2] = make_float4(acc0[2].x*di, acc0[2].y*di, acc0[2].z*di, acc0[2].w*di);
      o[3] = make_float4(acc0[3].x*di, acc0[3].y*di, acc0[3].z*di, acc0[3].w*di);
    }
    if (r1 < NNODES) {
      const float di = dinv[r1];
      float4* o = (float4*)&hs[(size_t)r1 * HID];
      o[0] = make_float4(acc1[0].x*di, acc1[0].y*di, acc1[0].z*di, acc1[0].w*di);
      o[1] = make_float4(acc1[1].x*di, acc1[1].y*di, acc1[1].z*di, acc1[1].w*di);
      o[2] = make_float4(acc1[2].x*di, acc1[2].y*di, acc1[2].z*di, acc1[2].w*di);
      o[3] = make_float4(acc1[3].x*di, acc1[3].y*di, acc1[3].z*di, acc1[3].w*di);
    }
  }
}

// ---------------- counting-sort scatter: csr[pos] = src ----------------
__global__ void k_scatter(const int* __restrict__ src, const int* __restrict__ dst,
                          int* __restrict__ cursor, int* __restrict__ csr) {
  int e = blockIdx.x * blockDim.x + threadIdx.x;
  if (e >= NEDGES) return;
  int d = dst[e];
  int pos = atomicAdd(&cursor[d], 1);
  csr[pos] = src[e];
}

// ---------------- gather: one wave per node; 4 edge-reps x 16 channel-lanes ----------------
__global__ __launch_bounds__(256) void k_gather(const float* __restrict__ hs,
                                                const int* __restrict__ off,
                                                const int* __restrict__ cursor, // = off+cnt
                                                const int* __restrict__ csr,
                                                const float* __restrict__ dinv,
                                                const float* __restrict__ bconv,
                                                float* __restrict__ nodeout) {
  const int n = blockIdx.x * 4 + (threadIdx.x >> 6);
  if (n >= NNODES) return;
  const int lane = threadIdx.x & 63;
  const int rep = lane >> 4;          // 0..3 edge slot
  const int j = lane & 15;            // channel
  const int start = off[n];
  const int end = cursor[n];
  float acc = (rep == 0) ? hs[(size_t)n * HID + j] : 0.0f;   // self-loop term
  for (int e = start + rep; e < end; e += 4) {
    int s = csr[e];                    // broadcast within 16-lane group
    acc += hs[(size_t)s * HID + j];    // 64B contiguous per group
  }
  acc += __shfl_xor(acc, 16);
  acc += __shfl_xor(acc, 32);
  if (rep == 0)
    nodeout[(size_t)n * HID + j] = fmaxf(acc * dinv[n] + bconv[j], 0.0f);
}

// ---------------- pool: wave-uniform segmented reduce (batch sorted) ----------------
__global__ void k_pool(const float* __restrict__ nodeout, const int* __restrict__ batch,
                       float* __restrict__ gsum, float* __restrict__ gcnt) {
  int i = blockIdx.x * blockDim.x + threadIdx.x;
  const bool valid = i < NNODES;
  const int ic = valid ? i : (NNODES - 1);
  float4 a[4];
#pragma unroll
  for (int cg = 0; cg < 4; ++cg) {
    a[cg] = ((const float4*)nodeout)[ic * 4 + cg];
    if (!valid) a[cg] = make_float4(0.f, 0.f, 0.f, 0.f);
  }
  int g = valid ? batch[ic] : -1;
  int g0 = __shfl(g, 0);
  int g63 = __shfl(g, 63);
  if (g0 == g63 && g0 >= 0) {
#pragma unroll
    for (int cg = 0; cg < 4; ++cg) {
      float* p = (float*)&a[cg];
#pragma unroll
      for (int j = 0; j < 4; ++j) {
        float v = p[j];
        v += __shfl_xor(v, 1);  v += __shfl_xor(v, 2);  v += __shfl_xor(v, 4);
        v += __shfl_xor(v, 8);  v += __shfl_xor(v, 16); v += __shfl_xor(v, 32);
        p[j] = v;
      }
    }
    if ((threadIdx.x & 63) == 0) {
#pragma unroll
      for (int cg = 0; cg < 4; ++cg) {
        float* p = (float*)&a[cg];
        atomicAdd(&gsum[g0 * HID + cg * 4 + 0], p[0]);
        atomicAdd(&gsum[g0 * HID + cg * 4 + 1], p[1]);
        atomicAdd(&gsum[g0 * HID + cg * 4 + 2], p[2]);
        atomicAdd(&gsum[g0 * HID + cg * 4 + 3], p[3]);
      }
      atomicAdd(&gcnt[g0], 64.0f);
    }
  } else if (valid) {
#pragma unroll
    for (int cg = 0; cg < 4; ++cg) {
      float* p = (float*)&a[cg];
      atomicAdd(&gsum[g * HID + cg * 4 + 0], p[0]);
      atomicAdd(&gsum[g * HID + cg * 4 + 1], p[1]);
      atomicAdd(&gsum[g * HID + cg * 4 + 2], p[2]);
      atomicAdd(&gsum[g * HID + cg * 4 + 3], p[3]);
    }
    atomicAdd(&gcnt[g], 1.0f);
  }
}

// ---------------- final ----------------
__global__ void k_final(const float* __restrict__ gsum, const float* __restrict__ gcnt,
                        const float* __restrict__ Wcls, const float* __restrict__ bcls,
                        float* __restrict__ out) {
  int t = threadIdx.x;
  if (t >= NG * 2) return;
  int g = t >> 1, k = t & 1;
  float cnt = fmaxf(gcnt[g], 1.0f);
  float s = 0.f;
#pragma unroll
  for (int c = 0; c < HID; ++c) s += gsum[g * HID + c] * Wcls[c * 2 + k];
  out[t] = s / cnt + bcls[k];
}

extern "C" void kernel_launch(void* const* d_in, const int* in_sizes, int n_in,
                              void* d_out, int out_size, void* d_ws, size_t ws_size,
                              hipStream_t stream) {
  const float* x     = (const float*)d_in[0];
  const float* W     = (const float*)d_in[1];
  const float* bconv = (const float*)d_in[2];
  const float* Wcls  = (const float*)d_in[3];
  const float* bcls  = (const float*)d_in[4];
  const int*   ei    = (const int*)d_in[5];   // [2, E] flat: src then dst
  const int*   batch = (const int*)d_in[6];
  const int* esrc = ei;
  const int* edst = ei + NEDGES;

  char* w = (char*)d_ws;
  float* hs      = (float*)w;                     w += (size_t)NNODES * HID * 4;  // 6.4MB
  float* nodeout = (float*)w;                     w += (size_t)NNODES * HID * 4;  // 6.4MB
  float* dinv    = (float*)w;                     w += (size_t)NNODES * 4;
  int*   cnt     = (int*)w;                       w += (size_t)NNODES * 4;
  int*   off     = (int*)w;                       w += (size_t)NNODES * 4;
  int*   cursor  = (int*)w;                       w += (size_t)NNODES * 4;
  int*   bsum    = (int*)w;                       w += 512 * 4;
  float* gsum    = (float*)w;                     w += NG * HID * 4;
  float* gcnt    = (float*)w;                     w += NG * 4;
  int*   csr     = (int*)w;                       w += (size_t)NEDGES * 4;        // 12.8MB

  const int NB = (NNODES + 255) / 256;   // 391 scan blocks

  k_zero   <<<NB, 256, 0, stream>>>(cnt, gsum);
  k_hist   <<<(NEDGES + 255) / 256, 256, 0, stream>>>(edst, cnt);
  k_scanA  <<<NB, 256, 0, stream>>>(cnt, off, bsum);
  k_scanB  <<<1, 512, 0, stream>>>(bsum, NB);
  k_scanC  <<<NB, 256, 0, stream>>>(off, bsum, cnt, cursor, dinv);
  k_gemm   <<<(NNODES + 127) / 128, 256, 0, stream>>>(x, W, dinv, hs);
  k_scatter<<<(NEDGES + 255) / 256, 256, 0, stream>>>(esrc, edst, cursor, csr);
  k_gather <<<(NNODES + 3) / 4, 256, 0, stream>>>(hs, off, cursor, csr, dinv, bconv, nodeout);
  k_pool   <<<NB, 256, 0, stream>>>(nodeout, batch, gsum, gcnt);
  k_final  <<<1, 128, 0, stream>>>(gsum, gcnt, Wcls, bcls, (float*)d_out);
}